// Round 6
// baseline (451.237 us; speedup 1.0000x reference)
//
#include <hip/hip_runtime.h>

// RATSQL relation-aware transformer layer, MI355X.
// Round 25: 128x128 GEMM rewrite per the measured m97 ladder. R24: attn
// VALUBusy 22->15.7 but dur 99->95 -> attn latency-bound, freezing it.
// GEMM stack (~150us for 6.4 GFLOP ~= 45 TF) gets the known 2.5x structure:
// BM=BN=128 BK=64, 4 waves (2x2, 64x64/wave, acc[4][4]), global_load_lds
// width=16 with LINEAR LDS dest + inverse-XOR-swizzled GLOBAL source
// (rule #21), swizzled ds_read_b128 (2-way conflict = free), 32 MFMA/wave
// per K-step, 2-barrier loop. kvmode/bias/relu/split-K epilogues preserved.
// Also fixed latent OOB in cvt_bf_k (n was 4x element count).

typedef unsigned short ushortt;
typedef __attribute__((ext_vector_type(8))) short short8;
typedef __attribute__((ext_vector_type(4))) float f32x4;

__device__ __forceinline__ ushortt f2bf(float f) {
  union { float f; unsigned int u; } c; c.f = f;
  unsigned int r = c.u + 0x7fffu + ((c.u >> 16) & 1u);
  return (ushortt)(r >> 16);
}
__device__ __forceinline__ unsigned int pk2(float a, float b) {
  return (unsigned int)f2bf(a) | ((unsigned int)f2bf(b) << 16);
}

// async global->LDS, 16B per lane; LDS dest = wave-uniform base + lane*16
__device__ __forceinline__ void gl16(const ushortt* g, ushortt* l) {
  __builtin_amdgcn_global_load_lds(
      (const __attribute__((address_space(1))) unsigned int*)g,
      (__attribute__((address_space(3))) unsigned int*)l, 16, 0, 0);
}

// one launch: both layers' six weights -> [N][K] bf16 in wbuf
__global__ void wcvt_all_k(const float* __restrict__ Wq, const float* __restrict__ Wk,
                           const float* __restrict__ Wv, const float* __restrict__ Wo,
                           const float* __restrict__ W1, const float* __restrict__ W2,
                           ushortt* __restrict__ wbuf) {
  int i = blockIdx.x * blockDim.x + threadIdx.x;
  int st = gridDim.x * blockDim.x;
  for (; i < 1572864; i += st) {
    int l = (i >= 786432) ? 1 : 0;
    int e = i - (l ? 786432 : 0);
    size_t o_w = (size_t)l * 65536, o_w1 = (size_t)l * 262144;
    float v;
    if (e < 262144) {
      int which = e >> 16;
      int loc = e & 65535;
      int k = loc & 255, n = loc >> 8;
      const float* W = (which == 0) ? Wq : (which == 1) ? Wk : (which == 2) ? Wv : Wo;
      v = W[o_w + ((size_t)k << 8) + n];
    } else if (e < 524288) {
      int loc = e - 262144;
      int k = loc & 255, n = loc >> 8;
      v = W1[o_w1 + ((size_t)k << 10) + n];
    } else {
      int loc = e - 524288;
      int k = loc & 1023, n = loc >> 10;
      v = W2[o_w1 + ((size_t)k << 8) + n];
    }
    wbuf[i] = f2bf(v);
  }
}

// fp32 -> bf16, 8 elems/thread, vectorized (n = element count)
__global__ __launch_bounds__(256) void cvt_bf_k(
    const float* __restrict__ in, ushortt* __restrict__ out, int n) {
  int idx = (blockIdx.x * 256 + threadIdx.x) * 8;
  if (idx >= n) return;
  float4 f0 = *(const float4*)(in + idx);
  float4 f1 = *(const float4*)(in + idx + 4);
  uint4 u;
  u.x = pk2(f0.x, f0.y); u.y = pk2(f0.z, f0.w);
  u.z = pk2(f1.x, f1.y); u.w = pk2(f1.z, f1.w);
  *(uint4*)(out + idx) = u;
}

// pack rel+msk (16 MB int32) -> relc uint8 (2 MB): msk ? 128 : rel (REL=100<128)
// also transpose Ev (100x32) -> EvT (32x100) fp32
__global__ __launch_bounds__(256) void relpack_k(
    const int* __restrict__ rel, const int* __restrict__ msk,
    unsigned char* __restrict__ relc,
    const float* __restrict__ Ev, float* __restrict__ EvT) {
  int g = blockIdx.x * blockDim.x + threadIdx.x;  // 524288 groups of 4, exact
  const int4* r4 = (const int4*)rel;
  const int4* m4 = (const int4*)msk;
  int4 r = r4[g];
  int4 m = m4[g];
  unsigned int pk = (unsigned int)((m.x ? 128 : r.x) & 255)
                  | ((unsigned int)((m.y ? 128 : r.y) & 255) << 8)
                  | ((unsigned int)((m.z ? 128 : r.z) & 255) << 16)
                  | ((unsigned int)((m.w ? 128 : r.w) & 255) << 24);
  ((unsigned int*)relc)[g] = pk;
  if (g < 3200) {
    int d = g / 100, rr = g - d * 100;
    EvT[d * 100 + rr] = Ev[(rr << 5) + d];
  }
}

// ---------- MFMA GEMM: 128x128 tile, BK=64, 4 waves (2x2), gload_lds ----------
// LDS rows are 64 elems (128B). Swizzle: stored colbyte = logical ^ ((row&7)<<4)
// achieved by inverse-swizzling the GLOBAL source (LDS dest stays linear).
// kvmode 0: C fp32 / cbf bf16 row-major. 1: bf16 [d][j] (v). 2: bf16 [j][d] (k).
__device__ __forceinline__ void mg128_body(
    const ushortt* __restrict__ A, const ushortt* __restrict__ BT,
    const float* __restrict__ bias, size_t boff,
    float* __restrict__ C, ushortt* __restrict__ cbf,
    int m0, int n0, int N, int K, int kbeg, int kend, int relu, int kvmode)
{
  __shared__ ushortt As[128 * 64];   // 16 KB
  __shared__ ushortt Bs[128 * 64];   // 16 KB
  int tid = threadIdx.x;
  int wv = tid >> 6, lane = tid & 63;
  int quad = lane >> 4, mr = lane & 15;
  int wr = wv >> 1, wc = wv & 1;
  int r8 = lane >> 3;                // row within an 8-row load group
  int c8 = (lane & 7) ^ r8;          // inverse-swizzled source col group
  int rbase = wv << 5;               // this wave stages rows [rbase, rbase+32)

  f32x4 acc[4][4] = {};
  for (int k0 = kbeg; k0 < kend; k0 += 64) {
#pragma unroll
    for (int L = 0; L < 4; ++L) {
      int rg = rbase + (L << 3);
      gl16(A + (size_t)(m0 + rg + r8) * K + k0 + (c8 << 3), &As[rg << 6]);
      gl16(BT + (size_t)(n0 + rg + r8) * K + k0 + (c8 << 3), &Bs[rg << 6]);
    }
    __syncthreads();   // drains vmcnt(0): staged data visible
#pragma unroll
    for (int kh = 0; kh < 2; ++kh) {
      int colsw = ((kh << 5) + (quad << 3)) ^ ((mr & 7) << 3);
      short8 a[4], bb[4];
#pragma unroll
      for (int mf = 0; mf < 4; ++mf)
        a[mf] = *(const short8*)(&As[(((wr << 6) + (mf << 4) + mr) << 6) + colsw]);
#pragma unroll
      for (int nf = 0; nf < 4; ++nf)
        bb[nf] = *(const short8*)(&Bs[(((wc << 6) + (nf << 4) + mr) << 6) + colsw]);
#pragma unroll
      for (int mf = 0; mf < 4; ++mf)
#pragma unroll
        for (int nf = 0; nf < 4; ++nf)
          acc[mf][nf] = __builtin_amdgcn_mfma_f32_16x16x32_bf16(
              a[mf], bb[nf], acc[mf][nf], 0, 0, 0);
    }
    __syncthreads();   // all reads done before next stage overwrites
  }
#pragma unroll
  for (int mf = 0; mf < 4; ++mf) {
#pragma unroll
    for (int nf = 0; nf < 4; ++nf) {
#pragma unroll
      for (int r = 0; r < 4; ++r) {
        int m = m0 + (wr << 6) + (mf << 4) + (quad << 2) + r;
        int n = n0 + (wc << 6) + (nf << 4) + mr;
        float v = acc[mf][nf][r];
        if (bias) v += bias[boff + n];
        if (relu) v = fmaxf(v, 0.f);
        if (kvmode == 1) {
          int b = m >> 10, i = m & 1023, h = n >> 5, d = n & 31;
          cbf[(size_t)(((b << 3) + h) * 32 + d) * 1024 + i] = f2bf(v);
        } else if (kvmode == 2) {
          int b = m >> 10, i = m & 1023, h = n >> 5, d = n & 31;
          cbf[(size_t)(((b << 3) + h) * 1024 + i) * 32 + d] = f2bf(v);
        } else if (cbf) {
          cbf[(size_t)m * N + n] = f2bf(v);
        } else {
          C[(size_t)m * N + n] = v;
        }
      }
    }
  }
}

// split-K aware: gridDim.z = ksplit; z=0 -> C0 (+bias), z=1 -> C1 (no bias)
__global__ __launch_bounds__(256) void mgemm128_k(
    const ushortt* __restrict__ A, const ushortt* __restrict__ BT,
    const float* __restrict__ bias, size_t boff,
    float* __restrict__ C0, float* __restrict__ C1, ushortt* __restrict__ cbf,
    int N, int K, int relu)
{
  int kidx = blockIdx.z;
  int kc = K / gridDim.z;
  int kbeg = kidx * kc;
  mg128_body(A, BT, kidx ? nullptr : bias, boff,
             kidx ? C1 : C0, cbf,
             blockIdx.y << 7, blockIdx.x << 7, N, K, kbeg, kbeg + kc, relu, 0);
}

// fused QKV: sel 0 -> q fp32; sel 1 (Wk) -> k bf16 [j][d]; sel 2 (Wv) -> v bf16 [d][j]
__global__ __launch_bounds__(256) void mqkv128_k(
    const ushortt* __restrict__ xbf, const ushortt* __restrict__ WT,
    float* __restrict__ q, ushortt* __restrict__ kbf, ushortt* __restrict__ vTbf)
{
  int sel = blockIdx.x >> 1;
  const ushortt* BT = WT + (size_t)sel * 65536;
  int mode = (sel == 1) ? 2 : (sel == 2) ? 1 : 0;
  mg128_body(xbf, BT, nullptr, 0,
             (sel == 0) ? q : nullptr,
             (sel == 1) ? kbf : (sel == 2) ? vTbf : nullptr,
             blockIdx.y << 7, (blockIdx.x & 1) << 7, 256, 256, 0, 256, 0, mode);
}

// ---------- MFMA attention: block = (b, h, 8 i's), ~32.5 KB LDS ----------
__global__ __launch_bounds__(256) void attn_mf8_k(
    const float* __restrict__ q, const ushortt* __restrict__ kbf,
    const ushortt* __restrict__ vTbf, const float* __restrict__ Ek,
    const float* __restrict__ EvT, const unsigned char* __restrict__ relc,
    ushortt* __restrict__ out)
{
  __shared__ ushortt pbf[8 * 1028];    // 16.4 KB
  __shared__ float regA[1072];         // qs[8*33]+expq[8*101]; later pvpart[256]+pvtot[256]
  __shared__ float wbin[8 * 108];      // stride 108: 16B-aligned rows
  __shared__ float denom4[32];
  __shared__ uint4 rcs4[512];          // 8 KB: relc rows for this block

  unsigned char* rcs = (unsigned char*)rcs4;
  int tid = threadIdx.x;
  int wv = tid >> 6, lane = tid & 63;
  int quad = lane >> 4, mr = lane & 15;
  int tile = blockIdx.x & 127;
  int h = (blockIdx.x >> 7) & 7;
  int b = blockIdx.x >> 10;
  int i0 = tile << 3;

  float* qs = regA;            // [8][33]
  float* expq = regA + 264;    // [8][101]  = exp(q . Ek[r])

  // stage relc rows (one coalesced latency window, overlapped with qs/wbin)
  const uint4* rg = (const uint4*)(relc + (((size_t)b * 1024 + i0) << 10));
  uint4 rc0 = rg[tid];
  uint4 rc1 = rg[256 + tid];
  {
    int i = tid >> 5, d = tid & 31;    // 256 = 8*32 exact
    qs[i * 33 + d] = q[(((size_t)(b * 1024 + i0 + i) * 8 + h) << 5) + d]
                     * 0.17677669529663687f;
  }
  for (int p = tid; p < 864; p += 256) wbin[p] = 0.f;
  rcs4[tid] = rc0;
  rcs4[256 + tid] = rc1;
  __syncthreads();  // (1)

  for (int p = tid; p < 800; p += 256) {
    int i = p / 100, r = p - i * 100;
    const float* ep = Ek + (r << 5);
    float s = 0.f;
#pragma unroll
    for (int d = 0; d < 32; ++d) s += qs[i * 33 + d] * ep[d];
    expq[i * 101 + r] = __expf(s);
  }
  __syncthreads();  // (2)

  // A-frag (q): rows 0-7 = q rows, rows 8-15 = DUPLICATE q rows (mr&7) so
  // MFMA output rows 8-15 are valid copies -> full-lane epilogue.
  short8 qf;
#pragma unroll
  for (int jj = 0; jj < 8; ++jj)
    ((ushortt*)&qf)[jj] = f2bf(qs[(mr & 7) * 33 + quad * 8 + jj]);

  const ushortt* ks = kbf + ((size_t)(b * 8 + h) << 15);   // [j][d]
  const ushortt* vs = vTbf + ((size_t)(b * 8 + h) << 15);  // [d][j]

  // ---- scores: wave wv covers j-quarter (256 j's) as 8 double-tiles ----
  float psum[4] = {0.f, 0.f, 0.f, 0.f};
  int jbase = (wv * 16) << 4;
  short8 kfa = *(const short8*)(ks + ((size_t)(jbase + mr) << 5) + quad * 8);
  short8 kfb = *(const short8*)(ks + ((size_t)(jbase + 16 + mr) << 5) + quad * 8);
  int iq = (quad & 1) << 2;
  int jofs = ((quad >> 1) << 4) + mr;
#pragma unroll
  for (int t = 0; t < 8; ++t) {
    int j0 = jbase + (t << 5);
    short8 ka = kfa, kb = kfb;
    if (t < 7) {
      kfa = *(const short8*)(ks + ((size_t)(j0 + 32 + mr) << 5) + quad * 8);
      kfb = *(const short8*)(ks + ((size_t)(j0 + 48 + mr) << 5) + quad * 8);
    }
    f32x4 z = {};
    f32x4 sa = __builtin_amdgcn_mfma_f32_16x16x32_bf16(qf, ka, z, 0, 0, 0);
    f32x4 sb = __builtin_amdgcn_mfma_f32_16x16x32_bf16(qf, kb, z, 0, 0, 0);
    int j = j0 + jofs;
#pragma unroll
    for (int r = 0; r < 4; ++r) {
      int i = iq + r;
      float sv = (quad >= 2) ? sb[r] : sa[r];
      unsigned int c = rcs[i * 1024 + j];
      float p = 0.f;
      if (c < 128u) {
        p = __expf(sv) * expq[i * 101 + (int)c];
        atomicAdd(&wbin[i * 108 + (int)c], p);
      }
      psum[r] += p;
      pbf[i * 1028 + j] = f2bf(p);
    }
  }
#pragma unroll
  for (int r = 0; r < 4; ++r) {
    float s = psum[r];
    s += __shfl_xor(s, 1, 64);
    s += __shfl_xor(s, 2, 64);
    s += __shfl_xor(s, 4, 64);
    s += __shfl_xor(s, 8, 64);
    s += __shfl_xor(s, 32, 64);   // merge the two j-halves
    if (mr == 0 && quad < 2) denom4[wv * 8 + quad * 4 + r] = s;
  }
  __syncthreads();  // (3) pbf, wbin, denom complete; regA free

  // ---- PV: ntile = wv&1 (d0), khalf = wv>>1 (k0); A rows 8..15 alias 0..7 ----
  float* pvpart = regA;        // [2][8][16]
  float* pvtot  = regA + 256;  // [8][32]
  int d0 = (wv & 1) << 4;
  int k0 = (wv >> 1) << 9;
  int prow = (mr & 7) * 1028;
  f32x4 acc0 = {}, acc1 = {};
  short8 vf = *(const short8*)(vs + ((size_t)(d0 + mr) << 10) + k0 + quad * 8);
#pragma unroll
  for (int kt = 0; kt < 16; ++kt) {
    int kk = k0 + (kt << 5);
    short8 vcur = vf;
    if (kt < 15)
      vf = *(const short8*)(vs + ((size_t)(d0 + mr) << 10) + k0 + ((kt + 1) << 5) + quad * 8);
    short8 pf = *(const short8*)(&pbf[prow + kk + quad * 8]);
    if (kt & 1)
      acc1 = __builtin_amdgcn_mfma_f32_16x16x32_bf16(pf, vcur, acc1, 0, 0, 0);
    else
      acc0 = __builtin_amdgcn_mfma_f32_16x16x32_bf16(pf, vcur, acc0, 0, 0, 0);
  }
  f32x4 acc;
#pragma unroll
  for (int r = 0; r < 4; ++r) acc[r] = acc0[r] + acc1[r];
  if (wv >= 2 && quad < 2) {
#pragma unroll
    for (int r = 0; r < 4; ++r)
      pvpart[((wv & 1) << 7) + (quad * 4 + r) * 16 + mr] = acc[r];
  }
  __syncthreads();  // (4)
  if (wv < 2 && quad < 2) {
#pragma unroll
    for (int r = 0; r < 4; ++r) {
      int i = quad * 4 + r;
      pvtot[i * 32 + d0 + mr] = acc[r] + pvpart[((wv & 1) << 7) + i * 16 + mr];
    }
  }
  __syncthreads();  // (5)

  // ---- final: all 256 threads, i = tid>>5, d = tid&31; bf16 out ----
  {
    int i = tid >> 5, d = tid & 31;
    const float4* evt = (const float4*)(EvT + d * 100);
    const float4* wb4 = (const float4*)(&wbin[i * 108]);
    float e0 = 0.f, e1 = 0.f, e2 = 0.f, e3 = 0.f;
#pragma unroll
    for (int rq = 0; rq < 25; ++rq) {
      float4 e4 = evt[rq];
      float4 w4 = wb4[rq];
      e0 += w4.x * e4.x;
      e1 += w4.y * e4.y;
      e2 += w4.z * e4.z;
      e3 += w4.w * e4.w;
    }
    float ev = (e0 + e1) + (e2 + e3);
    float den = denom4[i] + denom4[8 + i] + denom4[16 + i] + denom4[24 + i];
    out[(((size_t)(b * 1024 + i0 + i) * 8 + h) << 5) + d] =
        f2bf((pvtot[i * 32 + d] + ev) / den);
  }
}

// ---------- residual (+2 partials) + LayerNorm; emits fp32 x, bf16 xbf ----------
__global__ __launch_bounds__(256) void ln_k(
    const float* __restrict__ x, const float* __restrict__ o,
    const float* __restrict__ o2,
    const float* __restrict__ g, const float* __restrict__ bta, size_t eoff,
    float* __restrict__ xo, ushortt* __restrict__ xbf, float* __restrict__ fout)
{
  __shared__ float red[256];
  int row = blockIdx.x, t = threadIdx.x;
  size_t idx = (size_t)row * 256 + t;
  float r = x[idx] + o[idx];
  if (o2) r += o2[idx];
  red[t] = r;
  __syncthreads();
  for (int off = 128; off > 0; off >>= 1) {
    if (t < off) red[t] += red[t + off];
    __syncthreads();
  }
  float mean = red[0] * (1.f / 256.f);
  __syncthreads();
  float dv = r - mean;
  red[t] = dv * dv;
  __syncthreads();
  for (int off = 128; off > 0; off >>= 1) {
    if (t < off) red[t] += red[t + off];
    __syncthreads();
  }
  float var = red[0] * (1.f / 256.f);
  float val = dv * rsqrtf(var + 1e-5f) * g[eoff + t] + bta[eoff + t];
  xo[idx] = val;
  xbf[idx] = f2bf(val);
  if (fout) fout[idx] = val;
}

extern "C" void kernel_launch(void* const* d_in, const int* in_sizes, int n_in,
                              void* d_out, int out_size, void* d_ws, size_t ws_size,
                              hipStream_t stream) {
  const float* inp  = (const float*)d_in[0];
  const float* Wq   = (const float*)d_in[1];
  const float* Wk   = (const float*)d_in[2];
  const float* Wv   = (const float*)d_in[3];
  const float* Wo   = (const float*)d_in[4];
  const float* bo   = (const float*)d_in[5];
  const float* W1   = (const float*)d_in[6];
  const float* b1   = (const float*)d_in[7];
  const float* W2   = (const float*)d_in[8];
  const float* b2   = (const float*)d_in[9];
  const float* ln1g = (const float*)d_in[10];
  const float* ln1b = (const float*)d_in[11];
  const float* ln2g = (const float*)d_in[12];
  const float* ln2b = (const float*)d_in[13];
  const float* Ek   = (const float*)d_in[14];
  const float* Ev   = (const float*)d_in[15];
  const int*   rel  = (const int*)d_in[16];
  const int*   msk  = (const int*)d_in[17];

  const size_t SZ = 524288;  // 2048*256
  float* x        = (float*)d_ws;               // 2 MB fp32
  float* q        = x + SZ;                     // 2 MB fp32
  ushortt* kbf    = (ushortt*)(q + SZ);         // 1 MB bf16 [j][d]
  ushortt* vTbf   = kbf + SZ;                   // 1 MB bf16 [d][j]
  ushortt* attnbf = vTbf + SZ;                  // 1 MB bf16 attn out
  ushortt* xbf    = attnbf + SZ;                // 1 MB bf16 x
  float* tmp      = (float*)(xbf + SZ);         // 2 MB fp32 partial 0
  ushortt* wbuf   = (ushortt*)(tmp + SZ);       // 3 MB (both layers' weights)
  unsigned char* relc = (unsigned char*)(wbuf + 1572864);  // 2 MB packed rel
  float* EvT      = (float*)(relc + 2097152);   // 12.8 KB (pad to 16 KB)
  float* tmp2     = (float*)((char*)EvT + 16384); // 2 MB fp32 partial 1
  ushortt* inpbf  = (ushortt*)tmp2;             // alias: dead before wo writes tmp2
  ushortt* ffh    = (ushortt*)q;                // 4 MB alias over q+kbf+vTbf

  dim3 blk(256);
  wcvt_all_k<<<3072, blk, 0, stream>>>(Wq, Wk, Wv, Wo, W1, W2, wbuf);
  relpack_k<<<2048, blk, 0, stream>>>(rel, msk, relc, Ev, EvT);
  cvt_bf_k<<<256, blk, 0, stream>>>(inp, inpbf, 524288);

  for (int l = 0; l < 2; ++l) {
    size_t o_b  = (size_t)l * 256;
    size_t o_b1 = (size_t)l * 1024;
    const ushortt* xinbf = (l == 0) ? inpbf : xbf;
    const float* xin = (l == 0) ? inp : x;
    ushortt* wl = wbuf + (size_t)l * 786432;

    // QKV: 3 sels x (2 n-tiles x 16 m-tiles) of 128^2
    mqkv128_k<<<dim3(6, 16), blk, 0, stream>>>(xinbf, wl, q, kbf, vTbf);

    attn_mf8_k<<<2048, blk, 0, stream>>>(q, kbf, vTbf, Ek, EvT, relc, attnbf);

    // wo-proj: split-K x2
    mgemm128_k<<<dim3(2, 16, 2), blk, 0, stream>>>(attnbf, wl + 196608,
                                                   bo, o_b, tmp, tmp2, nullptr,
                                                   256, 256, 0);
    ln_k<<<2048, blk, 0, stream>>>(xin, tmp, tmp2, ln1g, ln1b, o_b, x, xbf, nullptr);

    mgemm128_k<<<dim3(8, 16, 1), blk, 0, stream>>>(xbf, wl + 262144,
                                                   b1, o_b1, nullptr, nullptr, ffh,
                                                   1024, 256, 1);
    // ffn2: split-K x2
    mgemm128_k<<<dim3(2, 16, 2), blk, 0, stream>>>(ffh, wl + 524288,
                                                   b2, o_b, tmp, tmp2, nullptr,
                                                   256, 1024, 0);
    ln_k<<<2048, blk, 0, stream>>>(x, tmp, tmp2, ln2g, ln2b, o_b, x, xbf,
                                   (l == 1) ? (float*)d_out : nullptr);
  }
}

// Round 7
// 377.187 us; speedup vs baseline: 1.1963x; 1.1963x over previous
//
#include <hip/hip_runtime.h>

// RATSQL relation-aware transformer layer, MI355X.
// Round 26: R25 regressed (389->451) -- 128^2 tiles left 50-75% of CUs idle
// on these small GEMMs (96/64/128-block grids). Fill > per-block efficiency
// at M=2048,N<=1024. Revert to R24's 64^2 geometry (384-512 blocks), improve
// INSIDE the structure: BK 32->64 (half the barrier rounds; LDS 18.4KB still
// 8 blocks/CU) + register double-buffer staging (issue next round's 4xuint4
// right after barrier; store->LDS next round; latency hides under 32 MFMAs).
// Epilogues / wave mapping / attn byte-identical to R24.

typedef unsigned short ushortt;
typedef __attribute__((ext_vector_type(8))) short short8;
typedef __attribute__((ext_vector_type(4))) float f32x4;

__device__ __forceinline__ ushortt f2bf(float f) {
  union { float f; unsigned int u; } c; c.f = f;
  unsigned int r = c.u + 0x7fffu + ((c.u >> 16) & 1u);
  return (ushortt)(r >> 16);
}
__device__ __forceinline__ unsigned int pk2(float a, float b) {
  return (unsigned int)f2bf(a) | ((unsigned int)f2bf(b) << 16);
}

// one launch: both layers' six weights -> [N][K] bf16 in wbuf
__global__ void wcvt_all_k(const float* __restrict__ Wq, const float* __restrict__ Wk,
                           const float* __restrict__ Wv, const float* __restrict__ Wo,
                           const float* __restrict__ W1, const float* __restrict__ W2,
                           ushortt* __restrict__ wbuf) {
  int i = blockIdx.x * blockDim.x + threadIdx.x;
  int st = gridDim.x * blockDim.x;
  for (; i < 1572864; i += st) {
    int l = (i >= 786432) ? 1 : 0;
    int e = i - (l ? 786432 : 0);
    size_t o_w = (size_t)l * 65536, o_w1 = (size_t)l * 262144;
    float v;
    if (e < 262144) {
      int which = e >> 16;
      int loc = e & 65535;
      int k = loc & 255, n = loc >> 8;
      const float* W = (which == 0) ? Wq : (which == 1) ? Wk : (which == 2) ? Wv : Wo;
      v = W[o_w + ((size_t)k << 8) + n];
    } else if (e < 524288) {
      int loc = e - 262144;
      int k = loc & 255, n = loc >> 8;
      v = W1[o_w1 + ((size_t)k << 10) + n];
    } else {
      int loc = e - 524288;
      int k = loc & 1023, n = loc >> 10;
      v = W2[o_w1 + ((size_t)k << 8) + n];
    }
    wbuf[i] = f2bf(v);
  }
}

// fp32 -> bf16, 8 elems/thread, vectorized (n = element count)
__global__ __launch_bounds__(256) void cvt_bf_k(
    const float* __restrict__ in, ushortt* __restrict__ out, int n) {
  int idx = (blockIdx.x * 256 + threadIdx.x) * 8;
  if (idx >= n) return;
  float4 f0 = *(const float4*)(in + idx);
  float4 f1 = *(const float4*)(in + idx + 4);
  uint4 u;
  u.x = pk2(f0.x, f0.y); u.y = pk2(f0.z, f0.w);
  u.z = pk2(f1.x, f1.y); u.w = pk2(f1.z, f1.w);
  *(uint4*)(out + idx) = u;
}

// pack rel+msk (16 MB int32) -> relc uint8 (2 MB): msk ? 128 : rel (REL=100<128)
// also transpose Ev (100x32) -> EvT (32x100) fp32
__global__ __launch_bounds__(256) void relpack_k(
    const int* __restrict__ rel, const int* __restrict__ msk,
    unsigned char* __restrict__ relc,
    const float* __restrict__ Ev, float* __restrict__ EvT) {
  int g = blockIdx.x * blockDim.x + threadIdx.x;  // 524288 groups of 4, exact
  const int4* r4 = (const int4*)rel;
  const int4* m4 = (const int4*)msk;
  int4 r = r4[g];
  int4 m = m4[g];
  unsigned int pk = (unsigned int)((m.x ? 128 : r.x) & 255)
                  | ((unsigned int)((m.y ? 128 : r.y) & 255) << 8)
                  | ((unsigned int)((m.z ? 128 : r.z) & 255) << 16)
                  | ((unsigned int)((m.w ? 128 : r.w) & 255) << 24);
  ((unsigned int*)relc)[g] = pk;
  if (g < 3200) {
    int d = g / 100, rr = g - d * 100;
    EvT[d * 100 + rr] = Ev[(rr << 5) + d];
  }
}

// ---------- MFMA GEMM body: 64x64 tile, 4 waves, BK=64, reg double-buffer ----
// kvmode 0: C fp32 / cbf bf16 row-major. 1: bf16 [d][j] (v). 2: bf16 [j][d] (k).
__device__ __forceinline__ void mgemm_body(
    const ushortt* __restrict__ A, const ushortt* __restrict__ BT,
    const float* __restrict__ bias, size_t boff,
    float* __restrict__ C, ushortt* __restrict__ cbf,
    int m0, int n0, int N, int K, int kbeg, int kend, int relu, int kvmode)
{
  __shared__ ushortt As[64 * 72];   // 9.2 KB, +8 pad keeps b128 reads 2-way max
  __shared__ ushortt Bs[64 * 72];
  int tid = threadIdx.x;
  int wv = tid >> 6, lane = tid & 63;
  int quad = lane >> 4, mr = lane & 15;
  int sm = tid >> 2, k16 = (tid & 3) << 4;

  const ushortt* ap = A + (size_t)(m0 + sm) * K + k16;
  const ushortt* bp = BT + (size_t)(n0 + sm) * K + k16;

  // prefetch round 0
  uint4 ra0 = *(const uint4*)(ap + kbeg);
  uint4 ra1 = *(const uint4*)(ap + kbeg + 8);
  uint4 rb0 = *(const uint4*)(bp + kbeg);
  uint4 rb1 = *(const uint4*)(bp + kbeg + 8);

  f32x4 acc[4] = {};
  for (int k0 = kbeg; k0 < kend; k0 += 64) {
    *(uint4*)(&As[sm * 72 + k16])     = ra0;
    *(uint4*)(&As[sm * 72 + k16 + 8]) = ra1;
    *(uint4*)(&Bs[sm * 72 + k16])     = rb0;
    *(uint4*)(&Bs[sm * 72 + k16 + 8]) = rb1;
    __syncthreads();
    if (k0 + 64 < kend) {   // issue next round; waits hide under MFMAs
      ra0 = *(const uint4*)(ap + k0 + 64);
      ra1 = *(const uint4*)(ap + k0 + 72);
      rb0 = *(const uint4*)(bp + k0 + 64);
      rb1 = *(const uint4*)(bp + k0 + 72);
    }
#pragma unroll
    for (int kh = 0; kh < 2; ++kh) {
      short8 af = *(const short8*)(&As[(wv * 16 + mr) * 72 + (kh << 5) + quad * 8]);
#pragma unroll
      for (int nt = 0; nt < 4; ++nt) {
        short8 bf = *(const short8*)(&Bs[(nt * 16 + mr) * 72 + (kh << 5) + quad * 8]);
        acc[nt] = __builtin_amdgcn_mfma_f32_16x16x32_bf16(af, bf, acc[nt], 0, 0, 0);
      }
    }
    __syncthreads();
  }
#pragma unroll
  for (int nt = 0; nt < 4; ++nt) {
#pragma unroll
    for (int r = 0; r < 4; ++r) {
      int m = m0 + wv * 16 + quad * 4 + r;
      int n = n0 + nt * 16 + mr;
      float v = acc[nt][r];
      if (bias) v += bias[boff + n];
      if (relu) v = fmaxf(v, 0.f);
      if (kvmode == 1) {
        int b = m >> 10, i = m & 1023, h = n >> 5, d = n & 31;
        cbf[(size_t)(((b << 3) + h) * 32 + d) * 1024 + i] = f2bf(v);
      } else if (kvmode == 2) {
        int b = m >> 10, i = m & 1023, h = n >> 5, d = n & 31;
        cbf[(size_t)(((b << 3) + h) * 1024 + i) * 32 + d] = f2bf(v);
      } else if (cbf) {
        cbf[(size_t)m * N + n] = f2bf(v);
      } else {
        C[(size_t)m * N + n] = v;
      }
    }
  }
}

// split-K aware: gridDim.z = ksplit; z=0 -> C0 (+bias), z=1 -> C1 (no bias)
__global__ __launch_bounds__(256) void mgemm_k(
    const ushortt* __restrict__ A, const ushortt* __restrict__ BT,
    const float* __restrict__ bias, size_t boff,
    float* __restrict__ C0, float* __restrict__ C1, ushortt* __restrict__ cbf,
    int N, int K, int relu)
{
  int kidx = blockIdx.z;
  int kc = K / gridDim.z;
  int kbeg = kidx * kc;
  mgemm_body(A, BT, kidx ? nullptr : bias, boff,
             kidx ? C1 : C0, cbf,
             blockIdx.y * 64, blockIdx.x * 64, N, K, kbeg, kbeg + kc, relu, 0);
}

// fused QKV: sel 0 -> q fp32; sel 1 (Wk) -> k bf16 [j][d]; sel 2 (Wv) -> v bf16 [d][j]
__global__ __launch_bounds__(256) void mqkv_k(
    const ushortt* __restrict__ xbf, const ushortt* __restrict__ WT,
    float* __restrict__ q, ushortt* __restrict__ kbf, ushortt* __restrict__ vTbf)
{
  int sel = blockIdx.x >> 2;
  const ushortt* BT = WT + (size_t)sel * 65536;
  int mode = (sel == 1) ? 2 : (sel == 2) ? 1 : 0;
  mgemm_body(xbf, BT, nullptr, 0,
             (sel == 0) ? q : nullptr,
             (sel == 1) ? kbf : (sel == 2) ? vTbf : nullptr,
             blockIdx.y * 64, (blockIdx.x & 3) * 64, 256, 256, 0, 256, 0, mode);
}

// ---------- MFMA attention: block = (b, h, 8 i's), ~32.5 KB LDS ----------
__global__ __launch_bounds__(256) void attn_mf8_k(
    const float* __restrict__ q, const ushortt* __restrict__ kbf,
    const ushortt* __restrict__ vTbf, const float* __restrict__ Ek,
    const float* __restrict__ EvT, const unsigned char* __restrict__ relc,
    ushortt* __restrict__ out)
{
  __shared__ ushortt pbf[8 * 1028];    // 16.4 KB
  __shared__ float regA[1072];         // qs[8*33]+expq[8*101]; later pvpart[256]+pvtot[256]
  __shared__ float wbin[8 * 108];      // stride 108: 16B-aligned rows
  __shared__ float denom4[32];
  __shared__ uint4 rcs4[512];          // 8 KB: relc rows for this block

  unsigned char* rcs = (unsigned char*)rcs4;
  int tid = threadIdx.x;
  int wv = tid >> 6, lane = tid & 63;
  int quad = lane >> 4, mr = lane & 15;
  int tile = blockIdx.x & 127;
  int h = (blockIdx.x >> 7) & 7;
  int b = blockIdx.x >> 10;
  int i0 = tile << 3;

  float* qs = regA;            // [8][33]
  float* expq = regA + 264;    // [8][101]  = exp(q . Ek[r])

  // stage relc rows (one coalesced latency window, overlapped with qs/wbin)
  const uint4* rg = (const uint4*)(relc + (((size_t)b * 1024 + i0) << 10));
  uint4 rc0 = rg[tid];
  uint4 rc1 = rg[256 + tid];
  {
    int i = tid >> 5, d = tid & 31;    // 256 = 8*32 exact
    qs[i * 33 + d] = q[(((size_t)(b * 1024 + i0 + i) * 8 + h) << 5) + d]
                     * 0.17677669529663687f;
  }
  for (int p = tid; p < 864; p += 256) wbin[p] = 0.f;
  rcs4[tid] = rc0;
  rcs4[256 + tid] = rc1;
  __syncthreads();  // (1)

  for (int p = tid; p < 800; p += 256) {
    int i = p / 100, r = p - i * 100;
    const float* ep = Ek + (r << 5);
    float s = 0.f;
#pragma unroll
    for (int d = 0; d < 32; ++d) s += qs[i * 33 + d] * ep[d];
    expq[i * 101 + r] = __expf(s);
  }
  __syncthreads();  // (2)

  // A-frag (q): rows 0-7 = q rows, rows 8-15 = DUPLICATE q rows (mr&7) so
  // MFMA output rows 8-15 are valid copies -> full-lane epilogue.
  short8 qf;
#pragma unroll
  for (int jj = 0; jj < 8; ++jj)
    ((ushortt*)&qf)[jj] = f2bf(qs[(mr & 7) * 33 + quad * 8 + jj]);

  const ushortt* ks = kbf + ((size_t)(b * 8 + h) << 15);   // [j][d]
  const ushortt* vs = vTbf + ((size_t)(b * 8 + h) << 15);  // [d][j]

  // ---- scores: wave wv covers j-quarter (256 j's) as 8 double-tiles ----
  float psum[4] = {0.f, 0.f, 0.f, 0.f};
  int jbase = (wv * 16) << 4;
  short8 kfa = *(const short8*)(ks + ((size_t)(jbase + mr) << 5) + quad * 8);
  short8 kfb = *(const short8*)(ks + ((size_t)(jbase + 16 + mr) << 5) + quad * 8);
  int iq = (quad & 1) << 2;
  int jofs = ((quad >> 1) << 4) + mr;
#pragma unroll
  for (int t = 0; t < 8; ++t) {
    int j0 = jbase + (t << 5);
    short8 ka = kfa, kb = kfb;
    if (t < 7) {
      kfa = *(const short8*)(ks + ((size_t)(j0 + 32 + mr) << 5) + quad * 8);
      kfb = *(const short8*)(ks + ((size_t)(j0 + 48 + mr) << 5) + quad * 8);
    }
    f32x4 z = {};
    f32x4 sa = __builtin_amdgcn_mfma_f32_16x16x32_bf16(qf, ka, z, 0, 0, 0);
    f32x4 sb = __builtin_amdgcn_mfma_f32_16x16x32_bf16(qf, kb, z, 0, 0, 0);
    int j = j0 + jofs;
#pragma unroll
    for (int r = 0; r < 4; ++r) {
      int i = iq + r;
      float sv = (quad >= 2) ? sb[r] : sa[r];
      unsigned int c = rcs[i * 1024 + j];
      float p = 0.f;
      if (c < 128u) {
        p = __expf(sv) * expq[i * 101 + (int)c];
        atomicAdd(&wbin[i * 108 + (int)c], p);
      }
      psum[r] += p;
      pbf[i * 1028 + j] = f2bf(p);
    }
  }
#pragma unroll
  for (int r = 0; r < 4; ++r) {
    float s = psum[r];
    s += __shfl_xor(s, 1, 64);
    s += __shfl_xor(s, 2, 64);
    s += __shfl_xor(s, 4, 64);
    s += __shfl_xor(s, 8, 64);
    s += __shfl_xor(s, 32, 64);   // merge the two j-halves
    if (mr == 0 && quad < 2) denom4[wv * 8 + quad * 4 + r] = s;
  }
  __syncthreads();  // (3) pbf, wbin, denom complete; regA free

  // ---- PV: ntile = wv&1 (d0), khalf = wv>>1 (k0); A rows 8..15 alias 0..7 ----
  float* pvpart = regA;        // [2][8][16]
  float* pvtot  = regA + 256;  // [8][32]
  int d0 = (wv & 1) << 4;
  int k0 = (wv >> 1) << 9;
  int prow = (mr & 7) * 1028;
  f32x4 acc0 = {}, acc1 = {};
  short8 vf = *(const short8*)(vs + ((size_t)(d0 + mr) << 10) + k0 + quad * 8);
#pragma unroll
  for (int kt = 0; kt < 16; ++kt) {
    int kk = k0 + (kt << 5);
    short8 vcur = vf;
    if (kt < 15)
      vf = *(const short8*)(vs + ((size_t)(d0 + mr) << 10) + k0 + ((kt + 1) << 5) + quad * 8);
    short8 pf = *(const short8*)(&pbf[prow + kk + quad * 8]);
    if (kt & 1)
      acc1 = __builtin_amdgcn_mfma_f32_16x16x32_bf16(pf, vcur, acc1, 0, 0, 0);
    else
      acc0 = __builtin_amdgcn_mfma_f32_16x16x32_bf16(pf, vcur, acc0, 0, 0, 0);
  }
  f32x4 acc;
#pragma unroll
  for (int r = 0; r < 4; ++r) acc[r] = acc0[r] + acc1[r];
  if (wv >= 2 && quad < 2) {
#pragma unroll
    for (int r = 0; r < 4; ++r)
      pvpart[((wv & 1) << 7) + (quad * 4 + r) * 16 + mr] = acc[r];
  }
  __syncthreads();  // (4)
  if (wv < 2 && quad < 2) {
#pragma unroll
    for (int r = 0; r < 4; ++r) {
      int i = quad * 4 + r;
      pvtot[i * 32 + d0 + mr] = acc[r] + pvpart[((wv & 1) << 7) + i * 16 + mr];
    }
  }
  __syncthreads();  // (5)

  // ---- final: all 256 threads, i = tid>>5, d = tid&31; bf16 out ----
  {
    int i = tid >> 5, d = tid & 31;
    const float4* evt = (const float4*)(EvT + d * 100);
    const float4* wb4 = (const float4*)(&wbin[i * 108]);
    float e0 = 0.f, e1 = 0.f, e2 = 0.f, e3 = 0.f;
#pragma unroll
    for (int rq = 0; rq < 25; ++rq) {
      float4 e4 = evt[rq];
      float4 w4 = wb4[rq];
      e0 += w4.x * e4.x;
      e1 += w4.y * e4.y;
      e2 += w4.z * e4.z;
      e3 += w4.w * e4.w;
    }
    float ev = (e0 + e1) + (e2 + e3);
    float den = denom4[i] + denom4[8 + i] + denom4[16 + i] + denom4[24 + i];
    out[(((size_t)(b * 1024 + i0 + i) * 8 + h) << 5) + d] =
        f2bf((pvtot[i * 32 + d] + ev) / den);
  }
}

// ---------- residual (+2 partials) + LayerNorm; emits fp32 x, bf16 xbf ----------
__global__ __launch_bounds__(256) void ln_k(
    const float* __restrict__ x, const float* __restrict__ o,
    const float* __restrict__ o2,
    const float* __restrict__ g, const float* __restrict__ bta, size_t eoff,
    float* __restrict__ xo, ushortt* __restrict__ xbf, float* __restrict__ fout)
{
  __shared__ float red[256];
  int row = blockIdx.x, t = threadIdx.x;
  size_t idx = (size_t)row * 256 + t;
  float r = x[idx] + o[idx];
  if (o2) r += o2[idx];
  red[t] = r;
  __syncthreads();
  for (int off = 128; off > 0; off >>= 1) {
    if (t < off) red[t] += red[t + off];
    __syncthreads();
  }
  float mean = red[0] * (1.f / 256.f);
  __syncthreads();
  float dv = r - mean;
  red[t] = dv * dv;
  __syncthreads();
  for (int off = 128; off > 0; off >>= 1) {
    if (t < off) red[t] += red[t + off];
    __syncthreads();
  }
  float var = red[0] * (1.f / 256.f);
  float val = dv * rsqrtf(var + 1e-5f) * g[eoff + t] + bta[eoff + t];
  xo[idx] = val;
  xbf[idx] = f2bf(val);
  if (fout) fout[idx] = val;
}

extern "C" void kernel_launch(void* const* d_in, const int* in_sizes, int n_in,
                              void* d_out, int out_size, void* d_ws, size_t ws_size,
                              hipStream_t stream) {
  const float* inp  = (const float*)d_in[0];
  const float* Wq   = (const float*)d_in[1];
  const float* Wk   = (const float*)d_in[2];
  const float* Wv   = (const float*)d_in[3];
  const float* Wo   = (const float*)d_in[4];
  const float* bo   = (const float*)d_in[5];
  const float* W1   = (const float*)d_in[6];
  const float* b1   = (const float*)d_in[7];
  const float* W2   = (const float*)d_in[8];
  const float* b2   = (const float*)d_in[9];
  const float* ln1g = (const float*)d_in[10];
  const float* ln1b = (const float*)d_in[11];
  const float* ln2g = (const float*)d_in[12];
  const float* ln2b = (const float*)d_in[13];
  const float* Ek   = (const float*)d_in[14];
  const float* Ev   = (const float*)d_in[15];
  const int*   rel  = (const int*)d_in[16];
  const int*   msk  = (const int*)d_in[17];

  const size_t SZ = 524288;  // 2048*256
  float* x        = (float*)d_ws;               // 2 MB fp32
  float* q        = x + SZ;                     // 2 MB fp32
  ushortt* kbf    = (ushortt*)(q + SZ);         // 1 MB bf16 [j][d]
  ushortt* vTbf   = kbf + SZ;                   // 1 MB bf16 [d][j]
  ushortt* attnbf = vTbf + SZ;                  // 1 MB bf16 attn out
  ushortt* xbf    = attnbf + SZ;                // 1 MB bf16 x
  float* tmp      = (float*)(xbf + SZ);         // 2 MB fp32 partial 0
  ushortt* wbuf   = (ushortt*)(tmp + SZ);       // 3 MB (both layers' weights)
  unsigned char* relc = (unsigned char*)(wbuf + 1572864);  // 2 MB packed rel
  float* EvT      = (float*)(relc + 2097152);   // 12.8 KB (pad to 16 KB)
  float* tmp2     = (float*)((char*)EvT + 16384); // 2 MB fp32 partial 1
  ushortt* inpbf  = (ushortt*)tmp2;             // alias: dead before wo writes tmp2
  ushortt* ffh    = (ushortt*)q;                // 4 MB alias over q+kbf+vTbf

  dim3 blk(256);
  wcvt_all_k<<<3072, blk, 0, stream>>>(Wq, Wk, Wv, Wo, W1, W2, wbuf);
  relpack_k<<<2048, blk, 0, stream>>>(rel, msk, relc, Ev, EvT);
  cvt_bf_k<<<256, blk, 0, stream>>>(inp, inpbf, 524288);

  for (int l = 0; l < 2; ++l) {
    size_t o_b  = (size_t)l * 256;
    size_t o_b1 = (size_t)l * 1024;
    const ushortt* xinbf = (l == 0) ? inpbf : xbf;
    const float* xin = (l == 0) ? inp : x;
    ushortt* wl = wbuf + (size_t)l * 786432;

    mqkv_k<<<dim3(12, 32), blk, 0, stream>>>(xinbf, wl, q, kbf, vTbf);

    attn_mf8_k<<<2048, blk, 0, stream>>>(q, kbf, vTbf, Ek, EvT, relc, attnbf);

    // wo-proj: split-K x2 -> 256 blocks
    mgemm_k<<<dim3(4, 32, 2), blk, 0, stream>>>(attnbf, wl + 196608,
                                                bo, o_b, tmp, tmp2, nullptr,
                                                256, 256, 0);
    ln_k<<<2048, blk, 0, stream>>>(xin, tmp, tmp2, ln1g, ln1b, o_b, x, xbf, nullptr);

    mgemm_k<<<dim3(16, 32, 1), blk, 0, stream>>>(xbf, wl + 262144,
                                                 b1, o_b1, nullptr, nullptr, ffh,
                                                 1024, 256, 1);
    // ffn2: split-K x2 -> 256 blocks
    mgemm_k<<<dim3(4, 32, 2), blk, 0, stream>>>(ffh, wl + 524288,
                                                b2, o_b, tmp, tmp2, nullptr,
                                                256, 1024, 0);
    ln_k<<<2048, blk, 0, stream>>>(x, tmp, tmp2, ln2g, ln2b, o_b, x, xbf,
                                   (l == 1) ? (float*)d_out : nullptr);
  }
}